// Round 1
// baseline (168.567 us; speedup 1.0000x reference)
//
#include <hip/hip_runtime.h>
#include <hip/hip_bf16.h>
#include <math.h>

// ---------------------------------------------------------------------------
// SAContrastiveAdversarialLoss on MI355X (gfx950)
// B=8192, D=128, S=64. Output: scalar fp32.
//
// loss = sum_i -log(1e-12 + num_i/denom_i) / (B*(2B-1))
//        + sum_i -log(1e-12 + 1 - picked_i)
// num_i   = exp(10*cos(z1_i, z2_i))
// denom_i = sum_k exp(10*cos(z1_i,z2_k)) + sum_k exp(10*cos(z1_i,z1_k))
//           - exp(10*cos(z1_i,z1_i))
// picked_i = normalize(c_i)[argmax(label_i)]
// ---------------------------------------------------------------------------

#define NROWS 8192
#define DFEAT 128

typedef __bf16 bf16_t;
typedef __bf16 bf16x8 __attribute__((ext_vector_type(8)));
typedef __bf16 bf16x2 __attribute__((ext_vector_type(2)));
typedef float  f32x4  __attribute__((ext_vector_type(4)));

__device__ __forceinline__ float fexp2(float x) {
#if __has_builtin(__builtin_amdgcn_exp2f)
  return __builtin_amdgcn_exp2f(x);
#else
  return exp2f(x);
#endif
}

// ---------------------------------------------------------------------------
// init: zero T accumulator and the output scalar (harness poisons them 0xAA)
__global__ void sa_init_kernel(float* __restrict__ T, float* __restrict__ out) {
  int i = blockIdx.x * 256 + threadIdx.x;
  if (i < NROWS) T[i] = 0.0f;
  if (i == 0) out[0] = 0.0f;
}

// ---------------------------------------------------------------------------
// prep: one wave per row. Computes row norms + diagonal dots, writes
//   Abuf[row] = bf16( n1 * 10*log2(e) )   (A operand, scale folded in)
//   Kc[row]         = bf16( n2 )          (keys for e12)
//   Kc[8192+row]    = bf16( n1 )          (keys for e11)
//   numv[row] = exp(10*cos(z1,z2)),  d11v[row] = exp(10*cos(z1,z1))
__global__ void sa_prep_kernel(const float* __restrict__ z1,
                               const float* __restrict__ z2,
                               bf16_t* __restrict__ Abuf,
                               bf16_t* __restrict__ Kc,
                               float* __restrict__ numv,
                               float* __restrict__ d11v) {
  int wave = threadIdx.x >> 6;
  int lane = threadIdx.x & 63;
  int row  = blockIdx.x * 4 + wave;

  const float2* z1p = (const float2*)(z1 + row * DFEAT);
  const float2* z2p = (const float2*)(z2 + row * DFEAT);
  float2 a = z1p[lane];
  float2 b = z2p[lane];

  float s1  = a.x * a.x + a.y * a.y;
  float s2  = b.x * b.x + b.y * b.y;
  float s12 = a.x * b.x + a.y * b.y;
#pragma unroll
  for (int m = 32; m; m >>= 1) {
    s1  += __shfl_xor(s1, m, 64);
    s2  += __shfl_xor(s2, m, 64);
    s12 += __shfl_xor(s12, m, 64);
  }
  float r1 = 1.0f / fmaxf(sqrtf(s1), 1e-8f);  // COS_EPS
  float r2 = 1.0f / fmaxf(sqrtf(s2), 1e-8f);

  const float SCL = 14.426950408889634f;  // 10 * log2(e), folds /tau + exp2

  bf16x2 av;  av[0] = (bf16_t)(a.x * r1 * SCL); av[1] = (bf16_t)(a.y * r1 * SCL);
  bf16x2 k2v; k2v[0] = (bf16_t)(b.x * r2);      k2v[1] = (bf16_t)(b.y * r2);
  bf16x2 k1v; k1v[0] = (bf16_t)(a.x * r1);      k1v[1] = (bf16_t)(a.y * r1);

  ((bf16x2*)(Abuf + row * DFEAT))[lane]            = av;
  ((bf16x2*)(Kc + row * DFEAT))[lane]              = k2v;
  ((bf16x2*)(Kc + (NROWS + row) * DFEAT))[lane]    = k1v;

  if (lane == 0) {
    numv[row] = expf(10.0f * s12 * r1 * r2);
    d11v[row] = expf(10.0f * s1 * r1 * r1);
  }
}

// ---------------------------------------------------------------------------
// main: fused "row-sum of exp(sim)" over the virtual 8192x16384 matrix.
// Each wave owns 64 query rows (A fragments held in VGPRs: 4 strips of 16)
// and a 512-column chunk of keys. Per 16-col tile: 4 B-frag global loads,
// 16 MFMAs, 16 exp2+add. MFMA C/D layout: col=lane&15, row=(lane>>4)*4+reg.
// A-operand: m=lane&15, k=(lane>>4)*8+j. B-operand: n=lane&15, k=(lane>>4)*8+j.
__global__ __launch_bounds__(256)
void sa_main_kernel(const bf16_t* __restrict__ Abuf,
                    const bf16_t* __restrict__ Kc,
                    float* __restrict__ T) {
  int wave = threadIdx.x >> 6;
  int lane = threadIdx.x & 63;
  int quad = lane >> 4;
  int l15  = lane & 15;

  int rowBase = blockIdx.x * 64;
  int chunk   = blockIdx.y * 4 + wave;   // 0..31
  int colBase = chunk * 512;

  // Load A fragments for 4 row-strips (held across the whole column loop)
  bf16x8 afrag[4][4];
#pragma unroll
  for (int s = 0; s < 4; ++s) {
    const bf16_t* ap = Abuf + (rowBase + s * 16 + l15) * DFEAT + quad * 8;
#pragma unroll
    for (int kf = 0; kf < 4; ++kf)
      afrag[s][kf] = *(const bf16x8*)(ap + kf * 32);
  }

  f32x4 sums[4];
#pragma unroll
  for (int s = 0; s < 4; ++s) sums[s] = (f32x4){0.f, 0.f, 0.f, 0.f};

  for (int ct = 0; ct < 32; ++ct) {
    int col = colBase + ct * 16 + l15;
    const bf16_t* bp = Kc + col * DFEAT + quad * 8;
    bf16x8 bfrag[4];
#pragma unroll
    for (int kf = 0; kf < 4; ++kf)
      bfrag[kf] = *(const bf16x8*)(bp + kf * 32);

#pragma unroll
    for (int s = 0; s < 4; ++s) {
      f32x4 c = {0.f, 0.f, 0.f, 0.f};
#pragma unroll
      for (int kf = 0; kf < 4; ++kf)
        c = __builtin_amdgcn_mfma_f32_16x16x32_bf16(afrag[s][kf], bfrag[kf], c,
                                                    0, 0, 0);
#pragma unroll
      for (int r = 0; r < 4; ++r)
        sums[s][r] += fexp2(c[r]);
    }
  }

  // Reduce across the 16 lanes of each quad-group (cols), then one lane
  // per quad commits 4 row partial-sums.
#pragma unroll
  for (int s = 0; s < 4; ++s) {
#pragma unroll
    for (int r = 0; r < 4; ++r) {
      float v = sums[s][r];
      v += __shfl_xor(v, 1, 64);
      v += __shfl_xor(v, 2, 64);
      v += __shfl_xor(v, 4, 64);
      v += __shfl_xor(v, 8, 64);
      if (l15 == 0)
        atomicAdd(&T[rowBase + s * 16 + quad * 4 + r], v);
    }
  }
}

// ---------------------------------------------------------------------------
// finalize: contrastive term from T, num, d11. One thread per row.
__global__ void sa_final_kernel(const float* __restrict__ T,
                                const float* __restrict__ numv,
                                const float* __restrict__ d11v,
                                float* __restrict__ out) {
  int i = blockIdx.x * 256 + threadIdx.x;
  float denom = T[i] - d11v[i];
  float v = -logf(1e-12f + numv[i] / denom);
  v *= (1.0f / 134209536.0f);  // 1 / (B*(2B-1)) = 1/(8192*16383)
#pragma unroll
  for (int m = 32; m; m >>= 1) v += __shfl_xor(v, m, 64);
  __shared__ float wsum[4];
  if ((threadIdx.x & 63) == 0) wsum[threadIdx.x >> 6] = v;
  __syncthreads();
  if (threadIdx.x == 0)
    atomicAdd(out, wsum[0] + wsum[1] + wsum[2] + wsum[3]);
}

// ---------------------------------------------------------------------------
// adversarial: one wave per row (S=64 == wave width).
__global__ void sa_adv_kernel(const float* __restrict__ c,
                              const float* __restrict__ lab,
                              float* __restrict__ out) {
  int wave = threadIdx.x >> 6;
  int lane = threadIdx.x & 63;
  int row  = blockIdx.x * 4 + wave;

  float cv = c[row * 64 + lane];
  float lv = lab[row * 64 + lane];

  float ss = cv * cv;
  float bestv = lv;
  int   besti = lane;
#pragma unroll
  for (int m = 32; m; m >>= 1) {
    ss += __shfl_xor(ss, m, 64);
    float ov = __shfl_xor(bestv, m, 64);
    int   oi = __shfl_xor(besti, m, 64);
    if (ov > bestv || (ov == bestv && oi < besti)) { bestv = ov; besti = oi; }
  }
  float picked = __shfl(cv, besti, 64) / fmaxf(sqrtf(ss), 1e-12f);
  float term = -logf(1e-12f + 1.0f - picked);  // LAM = 1

  __shared__ float acc[4];
  if (lane == 0) acc[wave] = term;
  __syncthreads();
  if (threadIdx.x == 0)
    atomicAdd(out, acc[0] + acc[1] + acc[2] + acc[3]);
}

// ---------------------------------------------------------------------------
extern "C" void kernel_launch(void* const* d_in, const int* in_sizes, int n_in,
                              void* d_out, int out_size, void* d_ws,
                              size_t ws_size, hipStream_t stream) {
  const float* z1  = (const float*)d_in[0];  // [8192,128]
  const float* z2  = (const float*)d_in[1];  // [8192,128]
  const float* co  = (const float*)d_in[2];  // [8192,64]
  const float* lab = (const float*)d_in[3];  // [8192,64]
  float* out = (float*)d_out;

  char* ws = (char*)d_ws;
  bf16_t* Abuf = (bf16_t*)ws;                            // 8192*128*2 = 2 MB
  bf16_t* Kc   = (bf16_t*)(ws + 2u * 1024 * 1024);       // 16384*128*2 = 4 MB
  float*  T    = (float*)(ws + 6u * 1024 * 1024);        // 32 KB
  float*  numv = T + NROWS;
  float*  d11v = numv + NROWS;

  sa_init_kernel<<<32, 256, 0, stream>>>(T, out);
  sa_prep_kernel<<<NROWS / 4, 256, 0, stream>>>(z1, z2, Abuf, Kc, numv, d11v);
  sa_main_kernel<<<dim3(NROWS / 64, 8), 256, 0, stream>>>(Abuf, Kc, T);
  sa_final_kernel<<<NROWS / 256, 256, 0, stream>>>(T, numv, d11v, out);
  sa_adv_kernel<<<NROWS / 4, 256, 0, stream>>>(co, lab, out);
}